// Round 7
// baseline (50.805 us; speedup 1.0000x reference)
//
#include <hip/hip_runtime.h>
#include <stdint.h>

#define KDIM 2048
#define NEXP 64
#define MT   64              // tokens per block
#define NCH  64              // k-chunks of 32
#define NTHR 256             // 4 waves: 2 (token-half) x 2 (expert-half)
#define DA   4               // A prefetch depth (chunks)
#define DB   2               // B prefetch depth (chunks)

typedef _Float16 half8 __attribute__((ext_vector_type(8)));
typedef __fp16  fp16x2 __attribute__((ext_vector_type(2)));
typedef float f32x4 __attribute__((ext_vector_type(4)));

__device__ __forceinline__ uint32_t pkrtz(float a, float b) {
    fp16x2 h = __builtin_amdgcn_cvt_pkrtz(a, b);
    return __builtin_bit_cast(uint32_t, h);
}

struct HL { half8 h; half8 l; };

// split 8 f32 into f16 hi (exact mantissa-truncate) + f16 lo (rtz residual)
__device__ __forceinline__ HL split8(float4 a, float4 b) {
    float y[8] = {a.x, a.y, a.z, a.w, b.x, b.y, b.z, b.w};
    uint32_t hw[4], lw[4];
    #pragma unroll
    for (int i = 0; i < 4; ++i) {
        float y0 = y[2 * i], y1 = y[2 * i + 1];
        float h0 = __builtin_bit_cast(float, __builtin_bit_cast(uint32_t, y0) & 0xFFFFE000u);
        float h1 = __builtin_bit_cast(float, __builtin_bit_cast(uint32_t, y1) & 0xFFFFE000u);
        hw[i] = pkrtz(h0, h1);
        lw[i] = pkrtz(y0 - h0, y1 - h1);
    }
    HL r;
    uint4 hv = {hw[0], hw[1], hw[2], hw[3]};
    uint4 lv = {lw[0], lw[1], lw[2], lw[3]};
    r.h = __builtin_bit_cast(half8, hv);
    r.l = __builtin_bit_cast(half8, lv);
    return r;
}

// W[64][2048] f32 -> fragment-ordered Wh/Wl:
// element index ((s*4+g)*64 + lane)*8 + j  maps to  W[g*16+(lane&15)][s*32+(lane>>4)*8+j]
__global__ __launch_bounds__(256) void prep_w(const float* __restrict__ W,
                                              _Float16* __restrict__ Wh,
                                              _Float16* __restrict__ Wl) {
    int t = blockIdx.x * 256 + threadIdx.x;   // 16384 threads = (s,g,l)
    int l = t & 63;
    int g = (t >> 6) & 3;
    int s = t >> 8;
    int e = g * 16 + (l & 15);
    int k = s * 32 + ((l >> 4) << 3);
    const float4* src = reinterpret_cast<const float4*>(W + (size_t)e * KDIM + k);
    HL r = split8(src[0], src[1]);
    *reinterpret_cast<half8*>(Wh + (size_t)t * 8) = r.h;
    *reinterpret_cast<half8*>(Wl + (size_t)t * 8) = r.l;
}

__global__ __launch_bounds__(NTHR) void router_kernel(const float* __restrict__ x,
                                                      const _Float16* __restrict__ Wh,
                                                      const _Float16* __restrict__ Wl,
                                                      float* __restrict__ out_w,
                                                      float* __restrict__ out_i) {
    __shared__ float ss[MT][NEXP + 3];   // scores for top-2 only (17.2 KB)

    const int tid  = threadIdx.x;
    const int lane = tid & 63;
    const int wave = tid >> 6;
    const int wm   = wave >> 1;          // token half (32 tok)
    const int wn   = wave & 1;           // expert half (32 exp)
    const int tb   = blockIdx.x * MT;

    // A: per-lane fragment row pointers (msub 0/1), k-base (lane>>4)*8
    const float* xs0 = x + (size_t)(tb + wm * 32 + (lane & 15)) * KDIM + ((lane >> 4) << 3);
    const float* xs1 = xs0 + (size_t)16 * KDIM;
    // B: fragment-ordered, this wave's first group
    const size_t bbase = ((size_t)(wn * 2) * 64 + lane) * 8;

    f32x4 acc[2][2];
    #pragma unroll
    for (int m = 0; m < 2; ++m)
        #pragma unroll
        for (int n = 0; n < 2; ++n)
            acc[m][n] = (f32x4){0.f, 0.f, 0.f, 0.f};

    float4 axr[DA][2][2];                // [slot][msub][seg]
    half8  bhr[DB][2], blr[DB][2];       // [slot][nsub]

    auto LOADA = [&](int slot, int c) {
        const float4* p0 = reinterpret_cast<const float4*>(xs0 + c * 32);
        const float4* p1 = reinterpret_cast<const float4*>(xs1 + c * 32);
        axr[slot][0][0] = p0[0]; axr[slot][0][1] = p0[1];
        axr[slot][1][0] = p1[0]; axr[slot][1][1] = p1[1];
    };
    auto LOADB = [&](int slot, int c) {
        size_t base = (size_t)c * 4 * 64 * 8 + bbase;
        bhr[slot][0] = *reinterpret_cast<const half8*>(Wh + base);
        bhr[slot][1] = *reinterpret_cast<const half8*>(Wh + base + 64 * 8);
        blr[slot][0] = *reinterpret_cast<const half8*>(Wl + base);
        blr[slot][1] = *reinterpret_cast<const half8*>(Wl + base + 64 * 8);
    };
    auto COMPUTE = [&](int sa, int sb) {
        HL a0 = split8(axr[sa][0][0], axr[sa][0][1]);
        HL a1 = split8(axr[sa][1][0], axr[sa][1][1]);
        half8 ah[2] = {a0.h, a1.h};
        half8 al[2] = {a0.l, a1.l};
        #pragma unroll
        for (int m = 0; m < 2; ++m)
            #pragma unroll
            for (int n = 0; n < 2; ++n) {
                acc[m][n] = __builtin_amdgcn_mfma_f32_16x16x32_f16(ah[m], bhr[sb][n], acc[m][n], 0, 0, 0);
                acc[m][n] = __builtin_amdgcn_mfma_f32_16x16x32_f16(al[m], bhr[sb][n], acc[m][n], 0, 0, 0);
                acc[m][n] = __builtin_amdgcn_mfma_f32_16x16x32_f16(ah[m], blr[sb][n], acc[m][n], 0, 0, 0);
            }
    };

    // prologue: fill rings
    #pragma unroll
    for (int i = 0; i < DA; ++i) LOADA(i, i);
    #pragma unroll
    for (int i = 0; i < DB; ++i) LOADB(i, i);

    // main: chunks 0..59, always prefetching (all ring indices static after unroll)
    for (int q = 0; q < 15; ++q) {
        #pragma unroll
        for (int i = 0; i < 4; ++i) {
            const int c = q * 4 + i;
            COMPUTE(i, i & 1);
            LOADA(i, c + DA);
            LOADB(i & 1, c + DB);
        }
    }
    // tail: chunks 60..63
    #pragma unroll
    for (int i = 0; i < 4; ++i) {
        const int c = 60 + i;
        COMPUTE(i, i & 1);
        if (c + DB < NCH) LOADB(i & 1, c + DB);   // static true for i<2
    }

    // ---- epilogue: top-2 per token ----
    #pragma unroll
    for (int m = 0; m < 2; ++m)
        #pragma unroll
        for (int n = 0; n < 2; ++n)
            #pragma unroll
            for (int r = 0; r < 4; ++r) {
                int tok = wm * 32 + m * 16 + (lane >> 4) * 4 + r;   // C/D: row=(lane>>4)*4+reg
                int e   = wn * 32 + n * 16 + (lane & 15);           //      col=lane&15 (m89)
                ss[tok][e] = acc[m][n][r];
            }
    __syncthreads();

    if (tid < MT) {
        const int t = tid;
        float m1 = -1e30f, m2 = -1e30f;
        int i1 = 0, i2 = 0;
        // strict '>' keeps the lower index on ties, matching jax.lax.top_k
        #pragma unroll
        for (int e = 0; e < NEXP; ++e) {
            float v = ss[t][e];
            if (v > m1) { m2 = m1; i2 = i1; m1 = v; i1 = e; }
            else if (v > m2) { m2 = v; i2 = e; }
        }
        const int gt = tb + t;
        out_w[gt * 2 + 0] = m1;
        out_w[gt * 2 + 1] = m2;
        out_i[gt * 2 + 0] = (float)i1;
        out_i[gt * 2 + 1] = (float)i2;
    }
}

extern "C" void kernel_launch(void* const* d_in, const int* in_sizes, int n_in,
                              void* d_out, int out_size, void* d_ws, size_t ws_size,
                              hipStream_t stream) {
    const float* x = (const float*)d_in[0];   // [16384, 2048] f32
    const float* W = (const float*)d_in[1];   // [64, 2048]   f32
    float* out = (float*)d_out;               // [16384*2 weights][16384*2 indices]

    const int n_tokens = in_sizes[0] / KDIM;  // 16384
    _Float16* Whp = (_Float16*)d_ws;          // 256 KB, fragment-ordered
    _Float16* Wlp = Whp + (size_t)NEXP * KDIM;

    hipLaunchKernelGGL(prep_w, dim3((NEXP * KDIM / 8) / 256), dim3(256), 0, stream, W, Whp, Wlp);
    hipLaunchKernelGGL(router_kernel, dim3(n_tokens / MT), dim3(NTHR), 0, stream,
                       x, Whp, Wlp, out, out + 2 * (size_t)n_tokens);
}

// Round 8
// 41.275 us; speedup vs baseline: 1.2309x; 1.2309x over previous
//
#include <hip/hip_runtime.h>
#include <stdint.h>

#define KDIM 2048
#define NEXP 64
#define MT   64              // tokens per block
#define KC   32              // k per chunk (one MFMA-K)
#define NCH  (KDIM / KC)     // 64 chunks
#define NTHR 256             // 4 waves

typedef _Float16 half8 __attribute__((ext_vector_type(8)));
typedef __fp16  fp16x2 __attribute__((ext_vector_type(2)));
typedef float f32x4 __attribute__((ext_vector_type(4)));

// W[64][2048] f32 -> Wh/Wl [64][2048] f16 (scaled by 256, hi/lo split)
__global__ __launch_bounds__(256) void prep_w(const float* __restrict__ W,
                                              _Float16* __restrict__ Wh,
                                              _Float16* __restrict__ Wl) {
    int idx = blockIdx.x * 256 + threadIdx.x;   // 131072 total
    float y = W[idx] * 256.0f;
    _Float16 h = (_Float16)y;
    _Float16 l = (_Float16)(y - (float)h);
    Wh[idx] = h;
    Wl[idx] = l;
}

// swizzled byte offset within one [64 rows][64B] LDS tensor
__device__ __forceinline__ int swz(int row, int byte_in_row) {
    return ((row << 6) + byte_in_row) ^ ((row & 14) << 3);
}

__device__ __forceinline__ uint32_t pkrtz(float a, float b) {
    fp16x2 h = __builtin_amdgcn_cvt_pkrtz(a, b);
    return __builtin_bit_cast(uint32_t, h);
}
__device__ __forceinline__ float lo_f(uint32_t u) {
    fp16x2 h = __builtin_bit_cast(fp16x2, u);
    return (float)h[0];
}
__device__ __forceinline__ float hi_f(uint32_t u) {
    fp16x2 h = __builtin_bit_cast(fp16x2, u);
    return (float)h[1];
}

// counted waits + raw barrier (T3/T4 minimum): loads stay in flight across barriers
#define VMCNT4() do { asm volatile("s_waitcnt vmcnt(4)" ::: "memory"); \
                      __builtin_amdgcn_sched_barrier(0); } while (0)
#define VMCNT0() do { asm volatile("s_waitcnt vmcnt(0)" ::: "memory"); \
                      __builtin_amdgcn_sched_barrier(0); } while (0)
#define LGKM_BAR() do { asm volatile("s_waitcnt lgkmcnt(0)" ::: "memory"); \
                        __builtin_amdgcn_sched_barrier(0);                 \
                        __builtin_amdgcn_s_barrier();                      \
                        __builtin_amdgcn_sched_barrier(0); } while (0)

__global__ __launch_bounds__(NTHR) void router_kernel(const float* __restrict__ x,
                                                      const _Float16* __restrict__ Wh,
                                                      const _Float16* __restrict__ Wl,
                                                      float* __restrict__ out_w,
                                                      float* __restrict__ out_i) {
    __shared__ char AsB[2][2][4096];   // [buf][h/l] x-tiles: 64 tok x 32 k f16
    __shared__ char BsB[2][2][4096];   // [buf][h/l] w-tiles: 64 exp x 32 k f16
    __shared__ float ss[MT][67];       // scores for top-2 (odd stride)

    const int tid  = threadIdx.x;
    const int lane = tid & 63;
    const int wave = tid >> 6;
    const int wm   = wave >> 1;        // 2x2 wave grid: 32-tok x 32-exp per wave
    const int wn   = wave & 1;
    const int tb   = blockIdx.x * MT;

    // ---- staging coords (identical to the validated R5 kernel) ----
    const int xrow0 = tid >> 3;                 // 0..31
    const int xseg  = tid & 7;
    const float* xsrc0 = x + (size_t)(tb + xrow0) * KDIM + xseg * 4;
    const float* xsrc1 = x + (size_t)(tb + xrow0 + 32) * KDIM + xseg * 4;
    const int xoff0 = swz(xrow0, xseg * 8);
    const int xoff1 = swz(xrow0 + 32, xseg * 8);
    const int wrr = tid >> 2;                   // expert row
    const int wss = tid & 3;                    // 16B segment
    const _Float16* wsrc0 = Wh + (size_t)wrr * KDIM + wss * 8;
    const _Float16* wsrc1 = Wl + (size_t)wrr * KDIM + wss * 8;
    const int woff = swz(wrr, wss * 16);

    // ---- compute-side read offsets ----
    const int kb = lane >> 4;
    const int ra0 = wm * 32 + (lane & 15);
    const int rb0 = wn * 32 + (lane & 15);
    const int aoff0 = swz(ra0,      kb * 16);
    const int aoff1 = swz(ra0 + 16, kb * 16);
    const int boff0 = swz(rb0,      kb * 16);
    const int boff1 = swz(rb0 + 16, kb * 16);

    f32x4 acc[2][2];
    #pragma unroll
    for (int i = 0; i < 2; ++i)
        #pragma unroll
        for (int j = 0; j < 2; ++j)
            acc[i][j] = (f32x4){0.f, 0.f, 0.f, 0.f};

    // two NAMED register prefetch sets (no runtime-indexed reg arrays)
    float4 Ax0, Ax1;  half8 Aw0, Aw1;   // set A
    float4 Bx0, Bx1;  half8 Bw0, Bw1;   // set B

#define LOADM(X0, X1, W0, W1, c)                                           \
    do {                                                                   \
        X0 = *reinterpret_cast<const float4*>(xsrc0 + (c) * KC);           \
        X1 = *reinterpret_cast<const float4*>(xsrc1 + (c) * KC);           \
        W0 = *reinterpret_cast<const half8*>(wsrc0 + (c) * KC);            \
        W1 = *reinterpret_cast<const half8*>(wsrc1 + (c) * KC);            \
    } while (0)

    auto STORE = [&](int b, float4 v0, float4 v1, half8 w0, half8 w1) {
        #pragma unroll
        for (int i = 0; i < 2; ++i) {
            float4 v = i ? v1 : v0;
            float y0 = v.x * 256.0f, y1 = v.y * 256.0f, y2 = v.z * 256.0f, y3 = v.w * 256.0f;
            uint32_t h01 = pkrtz(y0, y1);
            uint32_t h23 = pkrtz(y2, y3);
            float l0 = y0 - lo_f(h01), l1 = y1 - hi_f(h01);
            float l2 = y2 - lo_f(h23), l3 = y3 - hi_f(h23);
            uint32_t q01 = pkrtz(l0, l1);
            uint32_t q23 = pkrtz(l2, l3);
            uint2 hv, lv;
            hv.x = h01; hv.y = h23;
            lv.x = q01; lv.y = q23;
            int off = i ? xoff1 : xoff0;
            *reinterpret_cast<uint2*>(&AsB[b][0][0] + off) = hv;
            *reinterpret_cast<uint2*>(&AsB[b][1][0] + off) = lv;
        }
        *reinterpret_cast<half8*>(&BsB[b][0][0] + woff) = w0;
        *reinterpret_cast<half8*>(&BsB[b][1][0] + woff) = w1;
    };

    auto COMPUTE = [&](int b) {
        half8 ah[2], al[2], bh[2], bl[2];
        ah[0] = *reinterpret_cast<const half8*>(&AsB[b][0][0] + aoff0);
        ah[1] = *reinterpret_cast<const half8*>(&AsB[b][0][0] + aoff1);
        al[0] = *reinterpret_cast<const half8*>(&AsB[b][1][0] + aoff0);
        al[1] = *reinterpret_cast<const half8*>(&AsB[b][1][0] + aoff1);
        bh[0] = *reinterpret_cast<const half8*>(&BsB[b][0][0] + boff0);
        bh[1] = *reinterpret_cast<const half8*>(&BsB[b][0][0] + boff1);
        bl[0] = *reinterpret_cast<const half8*>(&BsB[b][1][0] + boff0);
        bl[1] = *reinterpret_cast<const half8*>(&BsB[b][1][0] + boff1);
        #pragma unroll
        for (int m = 0; m < 2; ++m)
            #pragma unroll
            for (int n = 0; n < 2; ++n) {
                acc[m][n] = __builtin_amdgcn_mfma_f32_16x16x32_f16(ah[m], bh[n], acc[m][n], 0, 0, 0);
                acc[m][n] = __builtin_amdgcn_mfma_f32_16x16x32_f16(al[m], bh[n], acc[m][n], 0, 0, 0);
                acc[m][n] = __builtin_amdgcn_mfma_f32_16x16x32_f16(ah[m], bl[n], acc[m][n], 0, 0, 0);
            }
    };

    // ---- prologue ----
    LOADM(Ax0, Ax1, Aw0, Aw1, 0);   // chunk 0 -> set A
    LOADM(Bx0, Bx1, Bw0, Bw1, 1);   // chunk 1 -> set B   (8 loads in flight)
    VMCNT4();                        // set A complete, set B still flying
    STORE(0, Ax0, Ax1, Aw0, Aw1);    // buf0 <- chunk 0
    LGKM_BAR();

    // ---- main loop: chunks 0..61, unrolled x2 for static buffer/set parity ----
    for (int q = 0; q < 31; ++q) {
        // chunk c = 2q (buf 0): compute, prefetch c+2 into A, store c+1 (set B) into buf1
        COMPUTE(0);
        LOADM(Ax0, Ax1, Aw0, Aw1, 2 * q + 2);
        VMCNT4();                    // chunk c+1 (set B) landed; c+2 still flying
        STORE(1, Bx0, Bx1, Bw0, Bw1);
        LGKM_BAR();
        // chunk c = 2q+1 (buf 1)
        COMPUTE(1);
        LOADM(Bx0, Bx1, Bw0, Bw1, 2 * q + 3);
        VMCNT4();
        STORE(0, Ax0, Ax1, Aw0, Aw1);
        LGKM_BAR();
    }
    // ---- tail: chunk 62 (buf 0), store chunk 63 (set B); chunk 63 (buf 1) ----
    COMPUTE(0);
    VMCNT0();
    STORE(1, Bx0, Bx1, Bw0, Bw1);
    LGKM_BAR();
    COMPUTE(1);

    // ---- epilogue: scale back (exact 2^-16) and top-2 per token ----
    const float sc = 1.0f / 65536.0f;
    #pragma unroll
    for (int m = 0; m < 2; ++m)
        #pragma unroll
        for (int n = 0; n < 2; ++n)
            #pragma unroll
            for (int r = 0; r < 4; ++r) {
                int tok = wm * 32 + m * 16 + (lane >> 4) * 4 + r;   // C/D: row=(lane>>4)*4+reg
                int e   = wn * 32 + n * 16 + (lane & 15);           //      col=lane&15  (m89)
                ss[tok][e] = acc[m][n][r] * sc;
            }
    __syncthreads();

    if (tid < MT) {
        const int t = tid;
        float m1 = -1e30f, m2 = -1e30f;
        int i1 = 0, i2 = 0;
        // strict '>' keeps the lower index on ties, matching jax.lax.top_k
        #pragma unroll
        for (int e = 0; e < NEXP; ++e) {
            float v = ss[t][e];
            if (v > m1) { m2 = m1; i2 = i1; m1 = v; i1 = e; }
            else if (v > m2) { m2 = v; i2 = e; }
        }
        const int gt = tb + t;
        out_w[gt * 2 + 0] = m1;
        out_w[gt * 2 + 1] = m2;
        out_i[gt * 2 + 0] = (float)i1;
        out_i[gt * 2 + 1] = (float)i2;
    }
#undef LOADM
}

extern "C" void kernel_launch(void* const* d_in, const int* in_sizes, int n_in,
                              void* d_out, int out_size, void* d_ws, size_t ws_size,
                              hipStream_t stream) {
    const float* x = (const float*)d_in[0];   // [16384, 2048] f32
    const float* W = (const float*)d_in[1];   // [64, 2048]   f32
    float* out = (float*)d_out;               // [16384*2 weights][16384*2 indices]

    const int n_tokens = in_sizes[0] / KDIM;  // 16384
    _Float16* Whp = (_Float16*)d_ws;          // 256 KB
    _Float16* Wlp = Whp + (size_t)NEXP * KDIM; // +256 KB

    hipLaunchKernelGGL(prep_w, dim3((NEXP * KDIM) / 256), dim3(256), 0, stream, W, Whp, Wlp);
    hipLaunchKernelGGL(router_kernel, dim3(n_tokens / MT), dim3(NTHR), 0, stream,
                       x, Whp, Wlp, out, out + 2 * (size_t)n_tokens);
}